// Round 14
// baseline (425.839 us; speedup 1.0000x reference)
//
#include <hip/hip_runtime.h>
#include <hip/hip_bf16.h>

#define NODES 50000
#define EDGES 800000
#define CH 128
#define NCOL 512           // table cols per node: [ym1 | ym2 | yv1 | yv2]
#define MPAD 50048         // 782 * 64
#define QROWS 64           // node-rows per k_gemmq block
#define EPW 4              // edge-PAIRS per wave (fallback kernel)

typedef __attribute__((ext_vector_type(8))) __bf16 bf16x8;
typedef __attribute__((ext_vector_type(4))) float f32x4;
typedef __attribute__((ext_vector_type(2))) float f32x2;
typedef unsigned long long u64;

static __device__ __forceinline__ unsigned short f2bf(float f) {
    union { float f; unsigned u; } v; v.f = f;
    unsigned r = v.u + 0x7FFFu + ((v.u >> 16) & 1u);   // RNE
    return (unsigned short)(r >> 16);
}

// ---- phase 0a: x fp32 -> bf16, padded to MPAD rows (pad rows = 0) ----
__global__ void k_cvt_x(const float* __restrict__ x, unsigned short* __restrict__ xb) {
    int i = blockIdx.x * blockDim.x + threadIdx.x;
    if (i >= MPAD * CH / 4) return;
    int base = i << 2;
    unsigned short s0 = 0, s1 = 0, s2 = 0, s3 = 0;
    if (base < NODES * CH) {
        const f32x4 v = *reinterpret_cast<const f32x4*>(x + base);
        s0 = f2bf(v[0]); s1 = f2bf(v[1]); s2 = f2bf(v[2]); s3 = f2bf(v[3]);
    }
    u64 p = (u64)s0 | ((u64)s1 << 16) | ((u64)s2 << 32) | ((u64)s3 << 48);
    *reinterpret_cast<u64*>(xb + base) = p;
}

// ---- phase 0b: Wb[512][128] bf16 (B^T). phys col n: ym1 | ym2 | yv1 | yv2 ----
__global__ void k_pack_w(const float* __restrict__ wm, const float* __restrict__ wv,
                         unsigned short* __restrict__ wb) {
    int i = blockIdx.x * blockDim.x + threadIdx.x;      // 0..65535
    if (i >= NCOL * CH) return;
    int n = i >> 7, k = i & 127;
    float v;
    if (n < 128)      v = wm[n * 256 + k];               // ym1 = w_mean[:, :128]
    else if (n < 256) v = wm[(n - 128) * 256 + 128 + k]; // ym2 = w_mean[:, 128:]
    else if (n < 384) v = wv[(n - 256) * 256 + k];       // yv1
    else              v = wv[(n - 384) * 256 + 128 + k]; // yv2
    wb[i] = f2bf(v);
}

// ---- phase 1 (fused GEMM + int8 quant), verified in R13 ----
__global__ __launch_bounds__(256) void k_gemmq(const unsigned short* __restrict__ xb,
                                               const unsigned short* __restrict__ wb,
                                               char* __restrict__ qt,
                                               float* __restrict__ sc) {
    __shared__ float sM[2][2][QROWS];
    __shared__ __align__(16) char sQ[QROWS][NCOL];
    const int lane = threadIdx.x & 63;
    const int wave = threadIdx.x >> 6;
    const int rowbase = blockIdx.x * QROWS;
    const int lr = lane & 15;
    const int kg = lane >> 4;

    f32x4 acc[4][8] = {};
#pragma unroll
    for (int ks = 0; ks < 4; ++ks) {
        const int k = ks * 32 + kg * 8;
        bf16x8 af[4], bfr[8];
#pragma unroll
        for (int a = 0; a < 4; ++a)
            af[a] = *reinterpret_cast<const bf16x8*>(xb + (size_t)(rowbase + a * 16 + lr) * CH + k);
#pragma unroll
        for (int b = 0; b < 8; ++b)
            bfr[b] = *reinterpret_cast<const bf16x8*>(wb + (size_t)(wave * 128 + lr * 8 + b) * CH + k);
#pragma unroll
        for (int a = 0; a < 4; ++a)
#pragma unroll
            for (int b = 0; b < 8; ++b)
                acc[a][b] = __builtin_amdgcn_mfma_f32_16x16x32_bf16(af[a], bfr[b], acc[a][b], 0, 0, 0);
    }

    const int crow = (lane >> 4) * 4;
    const int ccol = lane & 15;
    const int half = wave >> 1;

    float m[4][4];
#pragma unroll
    for (int a = 0; a < 4; ++a)
#pragma unroll
        for (int j = 0; j < 4; ++j) {
            float mm = 0.f;
#pragma unroll
            for (int b = 0; b < 8; ++b) mm = fmaxf(mm, fabsf(acc[a][b][j]));
            m[a][j] = mm;
        }
#pragma unroll
    for (int off = 1; off < 16; off <<= 1)
#pragma unroll
        for (int a = 0; a < 4; ++a)
#pragma unroll
            for (int j = 0; j < 4; ++j)
                m[a][j] = fmaxf(m[a][j], __shfl_xor(m[a][j], off, 16));
    if (ccol == 0)
#pragma unroll
        for (int a = 0; a < 4; ++a)
#pragma unroll
            for (int j = 0; j < 4; ++j)
                sM[half][wave & 1][a * 16 + crow + j] = m[a][j];
    __syncthreads();

#pragma unroll
    for (int a = 0; a < 4; ++a)
#pragma unroll
        for (int j = 0; j < 4; ++j) {
            const int row = a * 16 + crow + j;
            const float rm = fmaxf(sM[half][0][row], sM[half][1][row]);
            const float inv = (rm > 1e-20f) ? 127.0f / rm : 0.0f;
            u64 pk = 0;
#pragma unroll
            for (int b = 0; b < 8; ++b) {
                int q = __float2int_rn(acc[a][b][j] * inv);
                q = max(-127, min(127, q));
                pk |= (u64)((unsigned)q & 0xFFu) << (8 * b);
            }
            *reinterpret_cast<u64*>(&sQ[row][wave * 128 + ccol * 8]) = pk;
        }
    if (threadIdx.x < 2 * QROWS) {
        const int h = threadIdx.x >> 6, row = threadIdx.x & 63;
        const float rm = fmaxf(sM[h][0][row], sM[h][1][row]);
        sc[(size_t)(rowbase + row) * 2 + h] = (rm > 1e-20f) ? rm * (1.0f / 127.0f) : 1.0f;
    }
    __syncthreads();

#pragma unroll
    for (int t = 0; t < 8; ++t) {
        const int off = t * 4096 + threadIdx.x * 16;
        f32x4 v = *reinterpret_cast<const f32x4*>(&sQ[0][0] + off);
        *reinterpret_cast<f32x4*>(qt + (size_t)rowbase * NCOL + off) = v;
    }
}

// ---- CSR build: counting sort of edges by r ----
__global__ void k_zero(unsigned* __restrict__ cnt) {
    int i = blockIdx.x * blockDim.x + threadIdx.x;
    if (i < NODES) cnt[i] = 0;
}
__global__ void k_histn(const int* __restrict__ ei, unsigned* __restrict__ cnt) {
    int e = blockIdx.x * 256 + threadIdx.x;             // 3125 blocks exact
    atomicAdd(&cnt[ei[e]], 1u);
}
// single-block exclusive scan of cnt[NODES] -> rowptr, cursor (256 thr x 196)
__global__ __launch_bounds__(256) void k_scan(const unsigned* __restrict__ cnt,
                                              unsigned* __restrict__ rowptr,
                                              unsigned* __restrict__ cursor) {
    __shared__ unsigned part[256];
    const int t = threadIdx.x;
    const int per = (NODES + 255) / 256;                // 196
    const int lo = t * per, hi = min(NODES, lo + per);
    unsigned s = 0;
    for (int i = lo; i < hi; ++i) s += cnt[i];
    part[t] = s;
    __syncthreads();
    for (int off = 1; off < 256; off <<= 1) {
        unsigned x = (t >= off) ? part[t - off] : 0;
        __syncthreads();
        part[t] += x;
        __syncthreads();
    }
    unsigned run = part[t] - s;
    for (int i = lo; i < hi; ++i) { rowptr[i] = run; cursor[i] = run; run += cnt[i]; }
}
__global__ void k_scatter(const int* __restrict__ ei, unsigned* __restrict__ cursor,
                          u64* __restrict__ packed) {
    int e = blockIdx.x * 256 + threadIdx.x;             // 3125 blocks exact
    int r = ei[e];
    unsigned c = (unsigned)ei[EDGES + e];
    unsigned pos = atomicAdd(&cursor[r], 1u);
    packed[pos] = (u64)c | ((u64)e << 32);
}

// ---- phase 2: one wave per node; r-side row loaded ONCE into registers ----
// lanes 0-31: mean (ym1[r]+ym2[c]); lanes 32-63: var (yv1[r]+yv2[c]).
__global__ __launch_bounds__(256) void k_edges_csr(const unsigned* __restrict__ rowptr,
                                                   const unsigned* __restrict__ cnt,
                                                   const u64* __restrict__ packed,
                                                   const char* __restrict__ qt,
                                                   const float* __restrict__ sc,
                                                   float* __restrict__ out) {
    const int wave = threadIdx.x >> 6;
    const int node = blockIdx.x * 4 + wave;             // 12500*4 = 50000 exact
    const int lane = threadIdx.x & 63;
    const int half = lane >> 5;
    const int j = lane & 31;
    const unsigned start = rowptr[node];
    const unsigned deg = cnt[node];
    const int ar = *reinterpret_cast<const int*>(qt + (size_t)node * NCOL + half * 256 + j * 4);
    const float s_r = sc[(size_t)node * 2 + half];
    const size_t ob = (size_t)half * ((size_t)EDGES * 128) + (size_t)j * 4;

    for (unsigned k0 = 0; k0 < deg; k0 += 4) {
        const int n = (int)min(4u, deg - k0);
        u64 pk[4];
#pragma unroll
        for (int i = 0; i < 4; ++i)
            if (i < n) pk[i] = packed[start + k0 + i];
        int ac[4]; float s_c[4]; unsigned ee[4];
#pragma unroll
        for (int i = 0; i < 4; ++i)
            if (i < n) {
                const unsigned c = (unsigned)(pk[i] & 0xFFFFFFFFu);
                ee[i] = (unsigned)(pk[i] >> 32);
                ac[i] = *reinterpret_cast<const int*>(
                    qt + (size_t)c * NCOL + 128 + half * 256 + j * 4);
                s_c[i] = sc[(size_t)c * 2 + half];
            }
#pragma unroll
        for (int i = 0; i < 4; ++i)
            if (i < n) {
                f32x4 v;
#pragma unroll
                for (int k = 0; k < 4; ++k) {
                    const int sh = 24 - 8 * k;
                    v[k] = s_r * (float)((ar << sh) >> 24)
                         + s_c[i] * (float)((ac[i] << sh) >> 24);
                }
                __builtin_nontemporal_store(v,
                    reinterpret_cast<f32x4*>(out + ob + (size_t)ee[i] * 128));
            }
    }
}

// ---- merged-pass fallback (ws too small for CSR scratch), verified in R13 ----
__global__ __launch_bounds__(256) void k_edges_m(const int* __restrict__ ei,
                                                 const char* __restrict__ qt,
                                                 const float* __restrict__ sc,
                                                 float* __restrict__ out) {
    const int wave = threadIdx.x >> 6;
    const int lane = threadIdx.x & 63;
    const int es = lane >> 5;
    const int j = lane & 31;
    const int ebase = (blockIdx.x * 4 + wave) * (2 * EPW);
    int rr[EPW], cc[EPW];
#pragma unroll
    for (int i = 0; i < EPW; ++i) {
        int e = ebase + 2 * i + es;
        rr[i] = ei[e];
        cc[i] = ei[EDGES + e];
    }
    int am[EPW], av[EPW], bm[EPW], bv[EPW];
    f32x2 sr[EPW], scl[EPW];
#pragma unroll
    for (int i = 0; i < EPW; ++i) {
        const char* qr = qt + (size_t)rr[i] * NCOL;
        const char* qc = qt + (size_t)cc[i] * NCOL;
        am[i] = *reinterpret_cast<const int*>(qr + j * 4);
        av[i] = *reinterpret_cast<const int*>(qr + 256 + j * 4);
        bm[i] = *reinterpret_cast<const int*>(qc + 128 + j * 4);
        bv[i] = *reinterpret_cast<const int*>(qc + 384 + j * 4);
        sr[i]  = *reinterpret_cast<const f32x2*>(sc + (size_t)rr[i] * 2);
        scl[i] = *reinterpret_cast<const f32x2*>(sc + (size_t)cc[i] * 2);
    }
#pragma unroll
    for (int i = 0; i < EPW; ++i) {
        const int e = ebase + 2 * i + es;
        f32x4 sm_, sv_;
#pragma unroll
        for (int k = 0; k < 4; ++k) {
            const int sh = 24 - 8 * k;
            sm_[k] = sr[i][0] * (float)((am[i] << sh) >> 24)
                   + scl[i][0] * (float)((bm[i] << sh) >> 24);
            sv_[k] = sr[i][1] * (float)((av[i] << sh) >> 24)
                   + scl[i][1] * (float)((bv[i] << sh) >> 24);
        }
        __builtin_nontemporal_store(sm_,
            reinterpret_cast<f32x4*>(out + (size_t)e * 128 + j * 4));
        __builtin_nontemporal_store(sv_,
            reinterpret_cast<f32x4*>(out + (size_t)EDGES * 128 + (size_t)e * 128 + j * 4));
    }
}

// ---- last-resort fallback: direct fp32 per-edge GEMV ----
__global__ void k_naive(const float* __restrict__ x, const int* __restrict__ ei,
                        const float* __restrict__ wm, const float* __restrict__ wv,
                        float* __restrict__ out) {
    __shared__ float xs[256];
    int e = blockIdx.x;
    int t = threadIdx.x;
    int r = ei[e], c = ei[EDGES + e];
    xs[t] = (t < 128) ? x[(size_t)r * 128 + t] : x[(size_t)c * 128 + (t - 128)];
    __syncthreads();
    const float* w = (t < 128) ? (wm + (size_t)t * 256) : (wv + (size_t)(t - 128) * 256);
    float acc = 0.f;
#pragma unroll 8
    for (int k = 0; k < 256; ++k) acc = fmaf(xs[k], w[k], acc);
    size_t ooff = (t < 128) ? ((size_t)e * 128 + t)
                            : ((size_t)EDGES * 128 + (size_t)e * 128 + (t - 128));
    out[ooff] = acc;
}

extern "C" void kernel_launch(void* const* d_in, const int* in_sizes, int n_in,
                              void* d_out, int out_size, void* d_ws, size_t ws_size,
                              hipStream_t stream) {
    const float* x  = (const float*)d_in[0];
    const int*   ei = (const int*)d_in[1];
    const float* wm = (const float*)d_in[2];
    const float* wv = (const float*)d_in[3];
    float* out = (float*)d_out;

    const size_t xb_b = (size_t)MPAD * CH * 2;      // 12,812,288
    const size_t wb_b = (size_t)NCOL * CH * 2;      //    131,072
    const size_t qt_b = (size_t)MPAD * NCOL;        // 25,624,576
    const size_t sc_b = (size_t)MPAD * 2 * 4;       //    400,384
    const size_t cnt_b = (size_t)NODES * 4;         //    200,000
    const size_t rp_b  = (size_t)NODES * 4;
    const size_t cur_b = (size_t)NODES * 4;
    const size_t pk_b  = (size_t)EDGES * 8;         //  6,400,000

    const size_t need_tab = xb_b + wb_b + qt_b + sc_b;          // ~39.0 MB
    const size_t need_csr = need_tab + cnt_b + rp_b + cur_b + pk_b;  // ~46.0 MB

    if (ws_size < need_tab) {            // correctness insurance only
        k_naive<<<EDGES, 256, 0, stream>>>(x, ei, wm, wv, out);
        return;
    }

    unsigned short* xb = (unsigned short*)d_ws;
    unsigned short* wb = (unsigned short*)((char*)d_ws + xb_b);
    char*           qt = (char*)d_ws + xb_b + wb_b;
    float*          sc = (float*)((char*)d_ws + xb_b + wb_b + qt_b);

    k_cvt_x<<<(MPAD * CH / 4 + 255) / 256, 256, 0, stream>>>(x, xb);
    k_pack_w<<<(NCOL * CH + 255) / 256, 256, 0, stream>>>(wm, wv, wb);
    k_gemmq<<<MPAD / QROWS, 256, 0, stream>>>(xb, wb, qt, sc);

    if (ws_size >= need_csr) {
        unsigned* cnt    = (unsigned*)((char*)d_ws + need_tab);
        unsigned* rowptr = (unsigned*)((char*)d_ws + need_tab + cnt_b);
        unsigned* cursor = (unsigned*)((char*)d_ws + need_tab + cnt_b + rp_b);
        u64*      packed = (u64*)    ((char*)d_ws + need_tab + cnt_b + rp_b + cur_b);
        k_zero<<<(NODES + 255) / 256, 256, 0, stream>>>(cnt);
        k_histn<<<EDGES / 256, 256, 0, stream>>>(ei, cnt);
        k_scan<<<1, 256, 0, stream>>>(cnt, rowptr, cursor);
        k_scatter<<<EDGES / 256, 256, 0, stream>>>(ei, cursor, packed);
        k_edges_csr<<<NODES / 4, 256, 0, stream>>>(rowptr, cnt, packed, qt, sc, out);
    } else {
        k_edges_m<<<EDGES / (4 * 2 * EPW), 256, 0, stream>>>(ei, qt, sc, out);
    }
}

// Round 15
// 234.969 us; speedup vs baseline: 1.8123x; 1.8123x over previous
//
#include <hip/hip_runtime.h>
#include <hip/hip_bf16.h>

#define NODES 50000
#define EDGES 800000
#define CH 128
#define NCOL 512           // table cols per node: [ym1 | ym2 | yv1 | yv2]
#define MPAD 50048         // 782 * 64
#define QROWS 64           // node-rows per k_gemmq block
#define EPW 4              // edge-PAIRS per wave (8 edges/wave)

typedef __attribute__((ext_vector_type(8))) __bf16 bf16x8;
typedef __attribute__((ext_vector_type(4))) float f32x4;
typedef __attribute__((ext_vector_type(2))) float f32x2;
typedef unsigned long long u64;

static __device__ __forceinline__ unsigned short f2bf(float f) {
    union { float f; unsigned u; } v; v.f = f;
    unsigned r = v.u + 0x7FFFu + ((v.u >> 16) & 1u);   // RNE
    return (unsigned short)(r >> 16);
}

// ---- phase 0: Wb[512][128] bf16 (B^T). phys col n: ym1 | ym2 | yv1 | yv2 ----
__global__ void k_pack_w(const float* __restrict__ wm, const float* __restrict__ wv,
                         unsigned short* __restrict__ wb) {
    int i = blockIdx.x * blockDim.x + threadIdx.x;      // 0..65535
    if (i >= NCOL * CH) return;
    int n = i >> 7, k = i & 127;
    float v;
    if (n < 128)      v = wm[n * 256 + k];               // ym1 = w_mean[:, :128]
    else if (n < 256) v = wm[(n - 128) * 256 + 128 + k]; // ym2 = w_mean[:, 128:]
    else if (n < 384) v = wv[(n - 256) * 256 + k];       // yv1
    else              v = wv[(n - 384) * 256 + 128 + k]; // yv2
    wb[i] = f2bf(v);
}

// A-fragment loader: read x fp32 directly, convert to bf16 in-register (zero pad rows)
static __device__ __forceinline__ bf16x8 load_a(const float* __restrict__ x, int row, int k) {
    union { u64 q[2]; bf16x8 f; } u;
    if (row < NODES) {
        const f32x4 v0 = *reinterpret_cast<const f32x4*>(x + (size_t)row * CH + k);
        const f32x4 v1 = *reinterpret_cast<const f32x4*>(x + (size_t)row * CH + k + 4);
        u.q[0] = (u64)f2bf(v0[0]) | ((u64)f2bf(v0[1]) << 16)
               | ((u64)f2bf(v0[2]) << 32) | ((u64)f2bf(v0[3]) << 48);
        u.q[1] = (u64)f2bf(v1[0]) | ((u64)f2bf(v1[1]) << 16)
               | ((u64)f2bf(v1[2]) << 32) | ((u64)f2bf(v1[3]) << 48);
    } else {
        u.q[0] = 0; u.q[1] = 0;
    }
    return u.f;
}

// ---- phase 1 (fused GEMM + int8 quant; fp32 x read directly): 64 rows x 512 cols.
// Wave w covers phys cols [128w,128w+128). B-perm: frag b, lane lr reads wb col
// (128w + 8*lr + b) => lane ccol's acc[a][b][j] holds row (rowbase+16a+crow+j),
// col (128w + 8*ccol + b): 8 consecutive cols/lane => u64 pack. Per-(row,half)
// max: shfl width-16 + LDS cross-wave combine. Verified structure (R13).
__global__ __launch_bounds__(256) void k_gemmq(const float* __restrict__ x,
                                               const unsigned short* __restrict__ wb,
                                               char* __restrict__ qt,
                                               float* __restrict__ sc) {
    __shared__ float sM[2][2][QROWS];
    __shared__ __align__(16) char sQ[QROWS][NCOL];
    const int lane = threadIdx.x & 63;
    const int wave = threadIdx.x >> 6;
    const int rowbase = blockIdx.x * QROWS;
    const int lr = lane & 15;
    const int kg = lane >> 4;

    f32x4 acc[4][8] = {};
#pragma unroll
    for (int ks = 0; ks < 4; ++ks) {
        const int k = ks * 32 + kg * 8;
        bf16x8 af[4], bfr[8];
#pragma unroll
        for (int a = 0; a < 4; ++a)
            af[a] = load_a(x, rowbase + a * 16 + lr, k);
#pragma unroll
        for (int b = 0; b < 8; ++b)
            bfr[b] = *reinterpret_cast<const bf16x8*>(wb + (size_t)(wave * 128 + lr * 8 + b) * CH + k);
#pragma unroll
        for (int a = 0; a < 4; ++a)
#pragma unroll
            for (int b = 0; b < 8; ++b)
                acc[a][b] = __builtin_amdgcn_mfma_f32_16x16x32_bf16(af[a], bfr[b], acc[a][b], 0, 0, 0);
    }

    const int crow = (lane >> 4) * 4;
    const int ccol = lane & 15;
    const int half = wave >> 1;

    float m[4][4];
#pragma unroll
    for (int a = 0; a < 4; ++a)
#pragma unroll
        for (int j = 0; j < 4; ++j) {
            float mm = 0.f;
#pragma unroll
            for (int b = 0; b < 8; ++b) mm = fmaxf(mm, fabsf(acc[a][b][j]));
            m[a][j] = mm;
        }
#pragma unroll
    for (int off = 1; off < 16; off <<= 1)
#pragma unroll
        for (int a = 0; a < 4; ++a)
#pragma unroll
            for (int j = 0; j < 4; ++j)
                m[a][j] = fmaxf(m[a][j], __shfl_xor(m[a][j], off, 16));
    if (ccol == 0)
#pragma unroll
        for (int a = 0; a < 4; ++a)
#pragma unroll
            for (int j = 0; j < 4; ++j)
                sM[half][wave & 1][a * 16 + crow + j] = m[a][j];
    __syncthreads();

#pragma unroll
    for (int a = 0; a < 4; ++a)
#pragma unroll
        for (int j = 0; j < 4; ++j) {
            const int row = a * 16 + crow + j;
            const float rm = fmaxf(sM[half][0][row], sM[half][1][row]);
            const float inv = (rm > 1e-20f) ? 127.0f / rm : 0.0f;
            u64 pk = 0;
#pragma unroll
            for (int b = 0; b < 8; ++b) {
                int q = __float2int_rn(acc[a][b][j] * inv);
                q = max(-127, min(127, q));
                pk |= (u64)((unsigned)q & 0xFFu) << (8 * b);
            }
            *reinterpret_cast<u64*>(&sQ[row][wave * 128 + ccol * 8]) = pk;
        }
    if (threadIdx.x < 2 * QROWS) {
        const int h = threadIdx.x >> 6, row = threadIdx.x & 63;
        const float rm = fmaxf(sM[h][0][row], sM[h][1][row]);
        sc[(size_t)(rowbase + row) * 2 + h] = (rm > 1e-20f) ? rm * (1.0f / 127.0f) : 1.0f;
    }
    __syncthreads();

#pragma unroll
    for (int t = 0; t < 8; ++t) {
        const int off = t * 4096 + threadIdx.x * 16;
        f32x4 v = *reinterpret_cast<const f32x4*>(&sQ[0][0] + off);
        *reinterpret_cast<f32x4*>(qt + (size_t)rowbase * NCOL + off) = v;
    }
}

// ---- phase 2: single merged pass over int8 table (both halves per edge) ----
// Verified in R13 (226.5 us). Per wave-instr, lanes 0-31 = edge e, 32-63 = e+1:
// writes are 1 KB contiguous per wave.
__global__ __launch_bounds__(256) void k_edges_m(const int* __restrict__ ei,
                                                 const char* __restrict__ qt,
                                                 const float* __restrict__ sc,
                                                 float* __restrict__ out) {
    const int wave = threadIdx.x >> 6;
    const int lane = threadIdx.x & 63;
    const int es = lane >> 5;
    const int j = lane & 31;
    const int ebase = (blockIdx.x * 4 + wave) * (2 * EPW);

    int rr[EPW], cc[EPW];
#pragma unroll
    for (int i = 0; i < EPW; ++i) {
        int e = ebase + 2 * i + es;
        rr[i] = ei[e];
        cc[i] = ei[EDGES + e];
    }
    int am[EPW], av[EPW], bm[EPW], bv[EPW];
    f32x2 sr[EPW], scl[EPW];
#pragma unroll
    for (int i = 0; i < EPW; ++i) {
        const char* qr = qt + (size_t)rr[i] * NCOL;
        const char* qc = qt + (size_t)cc[i] * NCOL;
        am[i] = *reinterpret_cast<const int*>(qr + j * 4);           // ym1[r]
        av[i] = *reinterpret_cast<const int*>(qr + 256 + j * 4);     // yv1[r]
        bm[i] = *reinterpret_cast<const int*>(qc + 128 + j * 4);     // ym2[c]
        bv[i] = *reinterpret_cast<const int*>(qc + 384 + j * 4);     // yv2[c]
        sr[i]  = *reinterpret_cast<const f32x2*>(sc + (size_t)rr[i] * 2);
        scl[i] = *reinterpret_cast<const f32x2*>(sc + (size_t)cc[i] * 2);
    }
#pragma unroll
    for (int i = 0; i < EPW; ++i) {
        const int e = ebase + 2 * i + es;
        f32x4 sm_, sv_;
#pragma unroll
        for (int k = 0; k < 4; ++k) {
            const int sh = 24 - 8 * k;
            sm_[k] = sr[i][0] * (float)((am[i] << sh) >> 24)
                   + scl[i][0] * (float)((bm[i] << sh) >> 24);
            sv_[k] = sr[i][1] * (float)((av[i] << sh) >> 24)
                   + scl[i][1] * (float)((bv[i] << sh) >> 24);
        }
        __builtin_nontemporal_store(sm_,
            reinterpret_cast<f32x4*>(out + (size_t)e * 128 + j * 4));
        __builtin_nontemporal_store(sv_,
            reinterpret_cast<f32x4*>(out + (size_t)EDGES * 128 + (size_t)e * 128 + j * 4));
    }
}

// ---- last-resort fallback: direct fp32 per-edge GEMV ----
__global__ void k_naive(const float* __restrict__ x, const int* __restrict__ ei,
                        const float* __restrict__ wm, const float* __restrict__ wv,
                        float* __restrict__ out) {
    __shared__ float xs[256];
    int e = blockIdx.x;
    int t = threadIdx.x;
    int r = ei[e], c = ei[EDGES + e];
    xs[t] = (t < 128) ? x[(size_t)r * 128 + t] : x[(size_t)c * 128 + (t - 128)];
    __syncthreads();
    const float* w = (t < 128) ? (wm + (size_t)t * 256) : (wv + (size_t)(t - 128) * 256);
    float acc = 0.f;
#pragma unroll 8
    for (int k = 0; k < 256; ++k) acc = fmaf(xs[k], w[k], acc);
    size_t ooff = (t < 128) ? ((size_t)e * 128 + t)
                            : ((size_t)EDGES * 128 + (size_t)e * 128 + (t - 128));
    out[ooff] = acc;
}

extern "C" void kernel_launch(void* const* d_in, const int* in_sizes, int n_in,
                              void* d_out, int out_size, void* d_ws, size_t ws_size,
                              hipStream_t stream) {
    const float* x  = (const float*)d_in[0];
    const int*   ei = (const int*)d_in[1];
    const float* wm = (const float*)d_in[2];
    const float* wv = (const float*)d_in[3];
    float* out = (float*)d_out;

    const size_t wb_b = (size_t)NCOL * CH * 2;      //    131,072
    const size_t qt_b = (size_t)MPAD * NCOL;        // 25,624,576
    const size_t sc_b = (size_t)MPAD * 2 * 4;       //    400,384

    if (ws_size < wb_b + qt_b + sc_b) {             // correctness insurance only
        k_naive<<<EDGES, 256, 0, stream>>>(x, ei, wm, wv, out);
        return;
    }

    unsigned short* wb = (unsigned short*)d_ws;
    char*           qt = (char*)d_ws + wb_b;
    float*          sc = (float*)((char*)d_ws + wb_b + qt_b);

    k_pack_w<<<(NCOL * CH + 255) / 256, 256, 0, stream>>>(wm, wv, wb);
    k_gemmq<<<MPAD / QROWS, 256, 0, stream>>>(x, wb, qt, sc);               // 782 blocks
    k_edges_m<<<EDGES / (4 * 2 * EPW), 256, 0, stream>>>(ei, qt, sc, out);  // 25000
}

// Round 16
// 225.871 us; speedup vs baseline: 1.8853x; 1.0403x over previous
//
#include <hip/hip_runtime.h>
#include <hip/hip_bf16.h>

#define NODES 50000
#define EDGES 800000
#define CH 128
#define NCOL 512           // int8 bytes per node row (interleaved layout, see below)
#define MPAD 50048         // 782 * 64
#define QROWS 64           // node-rows per k_gemmq block
#define EPW 4              // edge-PAIRS per wave (8 edges/wave)

// qt row layout (512 B per node), 4-byte chunks:
//   bytes [0,256)   r-side:  chunk 2t = ym1 cols[4t..4t+4), chunk 2t+1 = yv1 cols[4t..)
//   bytes [256,512) c-side:  chunk 2t = ym2 cols[4t..4t+4), chunk 2t+1 = yv2 cols[4t..)
// => edge gather = 2 contiguous 256B wave-requests (u64/lane), vs 4x128B before.

typedef __attribute__((ext_vector_type(8))) __bf16 bf16x8;
typedef __attribute__((ext_vector_type(4))) float f32x4;
typedef __attribute__((ext_vector_type(2))) float f32x2;
typedef unsigned long long u64;

static __device__ __forceinline__ unsigned short f2bf(float f) {
    union { float f; unsigned u; } v; v.f = f;
    unsigned r = v.u + 0x7FFFu + ((v.u >> 16) & 1u);   // RNE
    return (unsigned short)(r >> 16);
}

// ---- phase 0a: x fp32 -> bf16, padded to MPAD rows (pad rows = 0) ----
__global__ void k_cvt_x(const float* __restrict__ x, unsigned short* __restrict__ xb) {
    int i = blockIdx.x * blockDim.x + threadIdx.x;
    if (i >= MPAD * CH / 4) return;
    int base = i << 2;
    unsigned short s0 = 0, s1 = 0, s2 = 0, s3 = 0;
    if (base < NODES * CH) {
        const f32x4 v = *reinterpret_cast<const f32x4*>(x + base);
        s0 = f2bf(v[0]); s1 = f2bf(v[1]); s2 = f2bf(v[2]); s3 = f2bf(v[3]);
    }
    u64 p = (u64)s0 | ((u64)s1 << 16) | ((u64)s2 << 32) | ((u64)s3 << 48);
    *reinterpret_cast<u64*>(xb + base) = p;
}

// ---- phase 0b: Wb[512][128] bf16 (B^T). phys col n: ym1 | ym2 | yv1 | yv2 ----
__global__ void k_pack_w(const float* __restrict__ wm, const float* __restrict__ wv,
                         unsigned short* __restrict__ wb) {
    int i = blockIdx.x * blockDim.x + threadIdx.x;      // 0..65535
    if (i >= NCOL * CH) return;
    int n = i >> 7, k = i & 127;
    float v;
    if (n < 128)      v = wm[n * 256 + k];               // ym1 = w_mean[:, :128]
    else if (n < 256) v = wm[(n - 128) * 256 + 128 + k]; // ym2 = w_mean[:, 128:]
    else if (n < 384) v = wv[(n - 256) * 256 + k];       // yv1
    else              v = wv[(n - 384) * 256 + 128 + k]; // yv2
    wb[i] = f2bf(v);
}

// ---- phase 1 (fused GEMM + int8 quant), R13-verified; copy-out permutes to
// the interleaved layout. sQ internal layout stays [row][ym1|ym2|yv1|yv2].
__global__ __launch_bounds__(256) void k_gemmq(const unsigned short* __restrict__ xb,
                                               const unsigned short* __restrict__ wb,
                                               char* __restrict__ qt,
                                               float* __restrict__ sc) {
    __shared__ float sM[2][2][QROWS];
    __shared__ __align__(16) char sQ[QROWS][NCOL];
    const int lane = threadIdx.x & 63;
    const int wave = threadIdx.x >> 6;
    const int rowbase = blockIdx.x * QROWS;
    const int lr = lane & 15;
    const int kg = lane >> 4;

    f32x4 acc[4][8] = {};
#pragma unroll
    for (int ks = 0; ks < 4; ++ks) {
        const int k = ks * 32 + kg * 8;
        bf16x8 af[4], bfr[8];
#pragma unroll
        for (int a = 0; a < 4; ++a)
            af[a] = *reinterpret_cast<const bf16x8*>(xb + (size_t)(rowbase + a * 16 + lr) * CH + k);
#pragma unroll
        for (int b = 0; b < 8; ++b)
            bfr[b] = *reinterpret_cast<const bf16x8*>(wb + (size_t)(wave * 128 + lr * 8 + b) * CH + k);
#pragma unroll
        for (int a = 0; a < 4; ++a)
#pragma unroll
            for (int b = 0; b < 8; ++b)
                acc[a][b] = __builtin_amdgcn_mfma_f32_16x16x32_bf16(af[a], bfr[b], acc[a][b], 0, 0, 0);
    }

    const int crow = (lane >> 4) * 4;
    const int ccol = lane & 15;
    const int half = wave >> 1;

    float m[4][4];
#pragma unroll
    for (int a = 0; a < 4; ++a)
#pragma unroll
        for (int j = 0; j < 4; ++j) {
            float mm = 0.f;
#pragma unroll
            for (int b = 0; b < 8; ++b) mm = fmaxf(mm, fabsf(acc[a][b][j]));
            m[a][j] = mm;
        }
#pragma unroll
    for (int off = 1; off < 16; off <<= 1)
#pragma unroll
        for (int a = 0; a < 4; ++a)
#pragma unroll
            for (int j = 0; j < 4; ++j)
                m[a][j] = fmaxf(m[a][j], __shfl_xor(m[a][j], off, 16));
    if (ccol == 0)
#pragma unroll
        for (int a = 0; a < 4; ++a)
#pragma unroll
            for (int j = 0; j < 4; ++j)
                sM[half][wave & 1][a * 16 + crow + j] = m[a][j];
    __syncthreads();

#pragma unroll
    for (int a = 0; a < 4; ++a)
#pragma unroll
        for (int j = 0; j < 4; ++j) {
            const int row = a * 16 + crow + j;
            const float rm = fmaxf(sM[half][0][row], sM[half][1][row]);
            const float inv = (rm > 1e-20f) ? 127.0f / rm : 0.0f;
            u64 pk = 0;
#pragma unroll
            for (int b = 0; b < 8; ++b) {
                int q = __float2int_rn(acc[a][b][j] * inv);
                q = max(-127, min(127, q));
                pk |= (u64)((unsigned)q & 0xFFu) << (8 * b);
            }
            *reinterpret_cast<u64*>(&sQ[row][wave * 128 + ccol * 8]) = pk;
        }
    if (threadIdx.x < 2 * QROWS) {
        const int h = threadIdx.x >> 6, row = threadIdx.x & 63;
        const float rm = fmaxf(sM[h][0][row], sM[h][1][row]);
        sc[(size_t)(rowbase + row) * 2 + h] = (rm > 1e-20f) ? rm * (1.0f / 127.0f) : 1.0f;
    }
    __syncthreads();

    // copy out 32 KB with per-row interleave permutation:
    // out chunk pair t (8B) = { mean_src[4t..4t+4), var_src[4t..4t+4) }
#pragma unroll
    for (int t = 0; t < 8; ++t) {
        const int off = t * 4096 + threadIdx.x * 16;    // byte offset in tile
        const int row = off >> 9;
        const int ro = off & 511;
        const int k0 = ro >> 2;                         // first 4B out-chunk (mult of 4)
        const int blk = k0 >> 6;                        // 0 = r-side, 1 = c-side
        const int t0 = (k0 & 63) >> 1;                  // pair index (even)
        const int mbase = blk ? 128 : 0;                // ym1 / ym2
        const int vbase = blk ? 384 : 256;              // yv1 / yv2
        unsigned m0 = *reinterpret_cast<const unsigned*>(&sQ[row][mbase + 4 * t0]);
        unsigned v0 = *reinterpret_cast<const unsigned*>(&sQ[row][vbase + 4 * t0]);
        unsigned m1 = *reinterpret_cast<const unsigned*>(&sQ[row][mbase + 4 * (t0 + 1)]);
        unsigned v1 = *reinterpret_cast<const unsigned*>(&sQ[row][vbase + 4 * (t0 + 1)]);
        uint4 ov = make_uint4(m0, v0, m1, v1);
        *reinterpret_cast<uint4*>(qt + (size_t)rowbase * NCOL + off) = ov;
    }
}

// ---- phase 2: merged pass, interleaved layout: 2 x 256B gather requests/edge ----
// Wave = 2 edges per iter (es = lane>>5), lane j in [0,32) owns cols [4j,4j+4).
__global__ __launch_bounds__(256) void k_edges_m(const int* __restrict__ ei,
                                                 const char* __restrict__ qt,
                                                 const float* __restrict__ sc,
                                                 float* __restrict__ out) {
    const int wave = threadIdx.x >> 6;
    const int lane = threadIdx.x & 63;
    const int es = lane >> 5;
    const int j = lane & 31;
    const int ebase = (blockIdx.x * 4 + wave) * (2 * EPW);

    int rr[EPW], cc[EPW];
#pragma unroll
    for (int i = 0; i < EPW; ++i) {
        int e = ebase + 2 * i + es;
        rr[i] = ei[e];
        cc[i] = ei[EDGES + e];
    }
    u64 ra[EPW], rc[EPW];
    f32x2 sr[EPW], scl[EPW];
#pragma unroll
    for (int i = 0; i < EPW; ++i) {
        ra[i] = *reinterpret_cast<const u64*>(qt + (size_t)rr[i] * NCOL + j * 8);        // [m4|v4]
        rc[i] = *reinterpret_cast<const u64*>(qt + (size_t)cc[i] * NCOL + 256 + j * 8);  // [m4|v4]
        sr[i]  = *reinterpret_cast<const f32x2*>(sc + (size_t)rr[i] * 2);
        scl[i] = *reinterpret_cast<const f32x2*>(sc + (size_t)cc[i] * 2);
    }
#pragma unroll
    for (int i = 0; i < EPW; ++i) {
        const int e = ebase + 2 * i + es;
        const int amw = (int)(unsigned)(ra[i] & 0xFFFFFFFFu);
        const int avw = (int)(unsigned)(ra[i] >> 32);
        const int bmw = (int)(unsigned)(rc[i] & 0xFFFFFFFFu);
        const int bvw = (int)(unsigned)(rc[i] >> 32);
        f32x4 sm_, sv_;
#pragma unroll
        for (int k = 0; k < 4; ++k) {
            const int sh = 24 - 8 * k;
            sm_[k] = sr[i][0] * (float)((amw << sh) >> 24)
                   + scl[i][0] * (float)((bmw << sh) >> 24);
            sv_[k] = sr[i][1] * (float)((avw << sh) >> 24)
                   + scl[i][1] * (float)((bvw << sh) >> 24);
        }
        __builtin_nontemporal_store(sm_,
            reinterpret_cast<f32x4*>(out + (size_t)e * 128 + j * 4));
        __builtin_nontemporal_store(sv_,
            reinterpret_cast<f32x4*>(out + (size_t)EDGES * 128 + (size_t)e * 128 + j * 4));
    }
}

// ---- last-resort fallback: direct fp32 per-edge GEMV ----
__global__ void k_naive(const float* __restrict__ x, const int* __restrict__ ei,
                        const float* __restrict__ wm, const float* __restrict__ wv,
                        float* __restrict__ out) {
    __shared__ float xs[256];
    int e = blockIdx.x;
    int t = threadIdx.x;
    int r = ei[e], c = ei[EDGES + e];
    xs[t] = (t < 128) ? x[(size_t)r * 128 + t] : x[(size_t)c * 128 + (t - 128)];
    __syncthreads();
    const float* w = (t < 128) ? (wm + (size_t)t * 256) : (wv + (size_t)(t - 128) * 256);
    float acc = 0.f;
#pragma unroll 8
    for (int k = 0; k < 256; ++k) acc = fmaf(xs[k], w[k], acc);
    size_t ooff = (t < 128) ? ((size_t)e * 128 + t)
                            : ((size_t)EDGES * 128 + (size_t)e * 128 + (t - 128));
    out[ooff] = acc;
}

extern "C" void kernel_launch(void* const* d_in, const int* in_sizes, int n_in,
                              void* d_out, int out_size, void* d_ws, size_t ws_size,
                              hipStream_t stream) {
    const float* x  = (const float*)d_in[0];
    const int*   ei = (const int*)d_in[1];
    const float* wm = (const float*)d_in[2];
    const float* wv = (const float*)d_in[3];
    float* out = (float*)d_out;

    const size_t xb_b = (size_t)MPAD * CH * 2;      // 12,812,288
    const size_t wb_b = (size_t)NCOL * CH * 2;      //    131,072
    const size_t qt_b = (size_t)MPAD * NCOL;        // 25,624,576
    const size_t sc_b = (size_t)MPAD * 2 * 4;       //    400,384

    if (ws_size < xb_b + wb_b + qt_b + sc_b) {      // correctness insurance only
        k_naive<<<EDGES, 256, 0, stream>>>(x, ei, wm, wv, out);
        return;
    }

    unsigned short* xb = (unsigned short*)d_ws;
    unsigned short* wb = (unsigned short*)((char*)d_ws + xb_b);
    char*           qt = (char*)d_ws + xb_b + wb_b;
    float*          sc = (float*)((char*)d_ws + xb_b + wb_b + qt_b);

    k_cvt_x<<<(MPAD * CH / 4 + 255) / 256, 256, 0, stream>>>(x, xb);
    k_pack_w<<<(NCOL * CH + 255) / 256, 256, 0, stream>>>(wm, wv, wb);
    k_gemmq<<<MPAD / QROWS, 256, 0, stream>>>(xb, wb, qt, sc);              // 782 blocks
    k_edges_m<<<EDGES / (4 * 2 * EPW), 256, 0, stream>>>(ei, qt, sc, out);  // 25000
}